// Round 7
// baseline (414.356 us; speedup 1.0000x reference)
//
#include <hip/hip_runtime.h>

#define N 8192
#define D 128
#define ALPHA 0.2f
#define RCAP 256   // per-row nnz capacity; E[nnz]=83, sd=9

// ---------------------------------------------------------------------------
// Kernel 1: H = X @ W^T + b ; s = H @ a_s ; r = H @ a_r   (unchanged)
// ---------------------------------------------------------------------------
__global__ __launch_bounds__(256) void linear_kernel(
    const float* __restrict__ X, const float* __restrict__ W,
    const float* __restrict__ b, const float* __restrict__ a_s,
    const float* __restrict__ a_r,
    float* __restrict__ H, float* __restrict__ sv, float* __restrict__ rv)
{
    __shared__ float Xs[128 * 36];
    __shared__ float Ws[64 * 132];

    const int tid = threadIdx.x;
    const int i0  = blockIdx.x * 32;

    for (int idx = tid; idx < 32 * 128; idx += 256) {
        const int row = idx >> 7, k = idx & 127;
        Xs[k * 36 + row] = X[(i0 + row) * D + k];
    }

    float acc[4][4] = {};
    const int ty = tid >> 5, tx = tid & 31;
    const int rbase = ty * 4, cbase = tx * 4;

    for (int kb = 0; kb < 2; ++kb) {
        __syncthreads();
        for (int idx = tid; idx < 64 * 128; idx += 256) {
            const int o = idx >> 6, kk = idx & 63;
            Ws[kk * 132 + o] = W[o * D + kb * 64 + kk];
        }
        __syncthreads();
        #pragma unroll
        for (int kk = 0; kk < 64; ++kk) {
            const float4 xv = *(const float4*)&Xs[(kb * 64 + kk) * 36 + rbase];
            const float4 wv = *(const float4*)&Ws[kk * 132 + cbase];
            const float xr[4] = {xv.x, xv.y, xv.z, xv.w};
            const float wc[4] = {wv.x, wv.y, wv.z, wv.w};
            #pragma unroll
            for (int r = 0; r < 4; ++r)
                #pragma unroll
                for (int c = 0; c < 4; ++c)
                    acc[r][c] += xr[r] * wc[c];
        }
    }

    const float4 bv  = *(const float4*)&b[cbase];
    const float4 asv = *(const float4*)&a_s[cbase];
    const float4 arv = *(const float4*)&a_r[cbase];
    #pragma unroll
    for (int r = 0; r < 4; ++r) {
        float4 h;
        h.x = acc[r][0] + bv.x;
        h.y = acc[r][1] + bv.y;
        h.z = acc[r][2] + bv.z;
        h.w = acc[r][3] + bv.w;
        *(float4*)&H[(size_t)(i0 + rbase + r) * D + cbase] = h;
        float ps = h.x * asv.x + h.y * asv.y + h.z * asv.z + h.w * asv.w;
        float pr = h.x * arv.x + h.y * arv.y + h.z * arv.z + h.w * arv.w;
        #pragma unroll
        for (int off = 16; off > 0; off >>= 1) {
            ps += __shfl_xor(ps, off);
            pr += __shfl_xor(pr, off);
        }
        if (tx == 0) {
            sv[i0 + rbase + r] = ps;
            rv[i0 + rbase + r] = pr;
        }
    }
}

// ---------------------------------------------------------------------------
// Kernel 2: pure-stream mask build, GRID-CONTIGUOUS SWEEP.
// A is treated as 65536 chunks of 4 KB. Wave wgid handles chunks
// c = it*8192 + wgid, so at any instant the grid's active footprint is a
// contiguous ~32 MB window sweeping memory (copy-like), NOT 8192 phase-
// locked 32KB-strided row walkers (R6: ~2.4 TB/s).
// Mask layout is IDENTICAL to R6: word index c*64+lane == row*512+it*64+lane,
// bit b of word covers col (c&7)*1024 + (b>>2)*256 + lane*4 + (b&3).
// ---------------------------------------------------------------------------
__global__ __launch_bounds__(256) void mask_kernel(
    const float* __restrict__ A, unsigned short* __restrict__ Mk)
{
    const int lane = threadIdx.x & 63;
    const int wgid = blockIdx.x * 4 + (threadIdx.x >> 6);   // 0..8191
    const float4* __restrict__ A4 = (const float4*)A;

    #pragma unroll 2
    for (int it = 0; it < 8; ++it) {
        const int    c  = it * 8192 + wgid;     // global 4 KB chunk id
        const size_t fb = (size_t)c * 256;      // float4 base of chunk
        const float4 a0 = A4[fb +   0 + lane];
        const float4 a1 = A4[fb +  64 + lane];
        const float4 a2 = A4[fb + 128 + lane];
        const float4 a3 = A4[fb + 192 + lane];
        unsigned m = 0;
        m |= (a0.x != 0.0f ? 1u : 0u) << 0;
        m |= (a0.y != 0.0f ? 1u : 0u) << 1;
        m |= (a0.z != 0.0f ? 1u : 0u) << 2;
        m |= (a0.w != 0.0f ? 1u : 0u) << 3;
        m |= (a1.x != 0.0f ? 1u : 0u) << 4;
        m |= (a1.y != 0.0f ? 1u : 0u) << 5;
        m |= (a1.z != 0.0f ? 1u : 0u) << 6;
        m |= (a1.w != 0.0f ? 1u : 0u) << 7;
        m |= (a2.x != 0.0f ? 1u : 0u) << 8;
        m |= (a2.y != 0.0f ? 1u : 0u) << 9;
        m |= (a2.z != 0.0f ? 1u : 0u) << 10;
        m |= (a2.w != 0.0f ? 1u : 0u) << 11;
        m |= (a3.x != 0.0f ? 1u : 0u) << 12;
        m |= (a3.y != 0.0f ? 1u : 0u) << 13;
        m |= (a3.z != 0.0f ? 1u : 0u) << 14;
        m |= (a3.w != 0.0f ? 1u : 0u) << 15;
        Mk[(size_t)c * 64 + lane] = (unsigned short)m;
    }
}

// ---------------------------------------------------------------------------
// Kernel 3: mask -> list -> softmax -> gather. ONE WAVE PER ROW. (unchanged)
// ---------------------------------------------------------------------------
__global__ __launch_bounds__(256, 8) void gather_kernel(
    const unsigned short* __restrict__ Mk, const float* __restrict__ H,
    const float* __restrict__ sv, const float* __restrict__ rv,
    float* __restrict__ out)
{
    __shared__ float2 s_l[4][RCAP];   // .x = weight, .y = column index (bits)

    const int wave = threadIdx.x >> 6;
    const int lane = threadIdx.x & 63;
    const int i    = blockIdx.x * 4 + wave;

    // lane holds mask words k = lane*8 .. lane*8+7 (one 16B load)
    const uint4 mw = ((const uint4*)(Mk + (size_t)i * 512))[lane];
    unsigned wv[4] = {mw.x, mw.y, mw.z, mw.w};

    const int c = __popc(wv[0]) + __popc(wv[1]) + __popc(wv[2]) + __popc(wv[3]);

    // single wave inclusive scan
    int scan = c;
    #pragma unroll
    for (int off = 1; off < 64; off <<= 1) {
        const int t = __shfl_up(scan, off);
        if (lane >= off) scan += t;
    }
    int base = scan - c;                 // exclusive offset
    int cnt  = __shfl(scan, 63);         // wave-uniform total
    cnt = (cnt < RCAP) ? cnt : RCAP;

    // scatter: decode set bits -> columns
    #pragma unroll
    for (int widx = 0; widx < 4; ++widx) {
        unsigned mm = wv[widx];
        while (mm) {
            const int p = __ffs(mm) - 1;
            mm &= mm - 1;
            const int k = lane * 8 + widx * 2 + (p >> 4);  // mask word index
            const int b = p & 15;
            const int col = ((k >> 6) << 10) + ((b >> 2) << 8) + ((k & 63) << 2) + (b & 3);
            if (base < RCAP) s_l[wave][base].y = __int_as_float(col);
            ++base;
        }
    }

    // ---- softmax (<=4 entries per lane) ----
    const float si = sv[i];
    float zv[4];
    #pragma unroll
    for (int k = 0; k < 4; ++k) {
        const int p = lane + 64 * k;
        const bool act = (p < cnt);
        const int j = act ? __float_as_int(s_l[wave][p].y) : 0;
        float z = si + rv[j];
        z = (z > 0.0f) ? z : ALPHA * z;
        zv[k] = act ? z : -3.0e38f;
    }
    float lm = fmaxf(fmaxf(zv[0], zv[1]), fmaxf(zv[2], zv[3]));
    #pragma unroll
    for (int off = 32; off > 0; off >>= 1) lm = fmaxf(lm, __shfl_xor(lm, off));

    float sl = 0.0f;
    float wv4[4];
    #pragma unroll
    for (int k = 0; k < 4; ++k) {
        const int p = lane + 64 * k;
        const float w = (p < cnt) ? __expf(zv[k] - lm) : 0.0f;
        wv4[k] = w;
        sl += w;
    }
    #pragma unroll
    for (int off = 32; off > 0; off >>= 1) sl += __shfl_xor(sl, off);
    const float inv = 1.0f / sl;

    #pragma unroll
    for (int k = 0; k < 4; ++k) {
        const int p = lane + 64 * k;
        if (p < cnt) s_l[wave][p].x = wv4[k] * inv;
    }

    // ---- weighted gather; each lane owns features 2*lane, 2*lane+1 ----
    float2 acc = make_float2(0.0f, 0.0f);
    const float* __restrict__ Hl = H + 2 * lane;
    #pragma unroll 4
    for (int p = 0; p < cnt; ++p) {
        const float2 wj = s_l[wave][p];               // one b64 broadcast read
        const int   j  = __float_as_int(wj.y);
        const float2 h = *(const float2*)&Hl[(size_t)j * D];
        acc.x += wj.x * h.x;
        acc.y += wj.x * h.y;
    }
    *(float2*)&out[(size_t)i * D + 2 * lane] = acc;
}

extern "C" void kernel_launch(void* const* d_in, const int* in_sizes, int n_in,
                              void* d_out, int out_size, void* d_ws, size_t ws_size,
                              hipStream_t stream) {
    const float* X   = (const float*)d_in[0];
    const float* A   = (const float*)d_in[1];
    const float* W   = (const float*)d_in[2];
    const float* b   = (const float*)d_in[3];
    const float* a_s = (const float*)d_in[4];
    const float* a_r = (const float*)d_in[5];
    float* out = (float*)d_out;

    float* H  = (float*)d_ws;                         // N*D floats   (4 MB)
    float* sv = H + (size_t)N * D;                    // N floats
    float* rv = sv + N;                               // N floats
    unsigned short* Mk = (unsigned short*)(rv + N);   // N*512 u16    (8 MB)

    linear_kernel<<<256, 256, 0, stream>>>(X, W, b, a_s, a_r, H, sv, rv);
    mask_kernel<<<N / 4, 256, 0, stream>>>(A, Mk);
    gather_kernel<<<N / 4, 256, 0, stream>>>(Mk, H, sv, rv, out);
}

// Round 9
// 383.499 us; speedup vs baseline: 1.0805x; 1.0805x over previous
//
#include <hip/hip_runtime.h>

#define N 8192
#define D 128
#define ALPHA 0.2f
#define RCAP 256   // per-row nnz capacity; E[nnz]=83, sd=9

typedef float fx4 __attribute__((ext_vector_type(4)));   // native vec type for nontemporal builtins

// ---------------------------------------------------------------------------
// Kernel 1: H = X @ W^T + b ; s = H @ a_s ; r = H @ a_r   (unchanged)
// ---------------------------------------------------------------------------
__global__ __launch_bounds__(256) void linear_kernel(
    const float* __restrict__ X, const float* __restrict__ W,
    const float* __restrict__ b, const float* __restrict__ a_s,
    const float* __restrict__ a_r,
    float* __restrict__ H, float* __restrict__ sv, float* __restrict__ rv)
{
    __shared__ float Xs[128 * 36];
    __shared__ float Ws[64 * 132];

    const int tid = threadIdx.x;
    const int i0  = blockIdx.x * 32;

    for (int idx = tid; idx < 32 * 128; idx += 256) {
        const int row = idx >> 7, k = idx & 127;
        Xs[k * 36 + row] = X[(i0 + row) * D + k];
    }

    float acc[4][4] = {};
    const int ty = tid >> 5, tx = tid & 31;
    const int rbase = ty * 4, cbase = tx * 4;

    for (int kb = 0; kb < 2; ++kb) {
        __syncthreads();
        for (int idx = tid; idx < 64 * 128; idx += 256) {
            const int o = idx >> 6, kk = idx & 63;
            Ws[kk * 132 + o] = W[o * D + kb * 64 + kk];
        }
        __syncthreads();
        #pragma unroll
        for (int kk = 0; kk < 64; ++kk) {
            const float4 xv = *(const float4*)&Xs[(kb * 64 + kk) * 36 + rbase];
            const float4 wv = *(const float4*)&Ws[kk * 132 + cbase];
            const float xr[4] = {xv.x, xv.y, xv.z, xv.w};
            const float wc[4] = {wv.x, wv.y, wv.z, wv.w};
            #pragma unroll
            for (int r = 0; r < 4; ++r)
                #pragma unroll
                for (int c = 0; c < 4; ++c)
                    acc[r][c] += xr[r] * wc[c];
        }
    }

    const float4 bv  = *(const float4*)&b[cbase];
    const float4 asv = *(const float4*)&a_s[cbase];
    const float4 arv = *(const float4*)&a_r[cbase];
    #pragma unroll
    for (int r = 0; r < 4; ++r) {
        float4 h;
        h.x = acc[r][0] + bv.x;
        h.y = acc[r][1] + bv.y;
        h.z = acc[r][2] + bv.z;
        h.w = acc[r][3] + bv.w;
        *(float4*)&H[(size_t)(i0 + rbase + r) * D + cbase] = h;
        float ps = h.x * asv.x + h.y * asv.y + h.z * asv.z + h.w * asv.w;
        float pr = h.x * arv.x + h.y * arv.y + h.z * arv.z + h.w * arv.w;
        #pragma unroll
        for (int off = 16; off > 0; off >>= 1) {
            ps += __shfl_xor(ps, off);
            pr += __shfl_xor(pr, off);
        }
        if (tx == 0) {
            sv[i0 + rbase + r] = ps;
            rv[i0 + rbase + r] = pr;
        }
    }
}

// ---------------------------------------------------------------------------
// Kernel 2: pure-stream mask build, grid-contiguous sweep + NONTEMPORAL loads
// (nt bit via native ext_vector_type: no L1/L2 allocation for the 256 MB
// one-shot stream — testing the L1-line-fill-throttle theory for ~2.4 TB/s).
// Mask layout unchanged: word c*64+lane, bit b covers
// col (c&7)*1024 + (b>>2)*256 + lane*4 + (b&3).
// ---------------------------------------------------------------------------
__global__ __launch_bounds__(256) void mask_kernel(
    const float* __restrict__ A, unsigned short* __restrict__ Mk)
{
    const int lane = threadIdx.x & 63;
    const int wgid = blockIdx.x * 4 + (threadIdx.x >> 6);   // 0..8191
    const fx4* __restrict__ A4 = (const fx4*)A;

    #pragma unroll 2
    for (int it = 0; it < 8; ++it) {
        const int    c  = it * 8192 + wgid;     // global 4 KB chunk id
        const size_t fb = (size_t)c * 256;      // float4 base of chunk
        const fx4 a0 = __builtin_nontemporal_load(&A4[fb +   0 + lane]);
        const fx4 a1 = __builtin_nontemporal_load(&A4[fb +  64 + lane]);
        const fx4 a2 = __builtin_nontemporal_load(&A4[fb + 128 + lane]);
        const fx4 a3 = __builtin_nontemporal_load(&A4[fb + 192 + lane]);
        unsigned m = 0;
        m |= (a0.x != 0.0f ? 1u : 0u) << 0;
        m |= (a0.y != 0.0f ? 1u : 0u) << 1;
        m |= (a0.z != 0.0f ? 1u : 0u) << 2;
        m |= (a0.w != 0.0f ? 1u : 0u) << 3;
        m |= (a1.x != 0.0f ? 1u : 0u) << 4;
        m |= (a1.y != 0.0f ? 1u : 0u) << 5;
        m |= (a1.z != 0.0f ? 1u : 0u) << 6;
        m |= (a1.w != 0.0f ? 1u : 0u) << 7;
        m |= (a2.x != 0.0f ? 1u : 0u) << 8;
        m |= (a2.y != 0.0f ? 1u : 0u) << 9;
        m |= (a2.z != 0.0f ? 1u : 0u) << 10;
        m |= (a2.w != 0.0f ? 1u : 0u) << 11;
        m |= (a3.x != 0.0f ? 1u : 0u) << 12;
        m |= (a3.y != 0.0f ? 1u : 0u) << 13;
        m |= (a3.z != 0.0f ? 1u : 0u) << 14;
        m |= (a3.w != 0.0f ? 1u : 0u) << 15;
        Mk[(size_t)c * 64 + lane] = (unsigned short)m;
    }
}

// ---------------------------------------------------------------------------
// Kernel 3: mask -> list -> softmax -> gather. ONE WAVE PER ROW.
// Gather phase: TWO entries per trip (lane>>5 = entry parity, lane&31 =
// float4 feature slot) -> ~42 trips instead of 83, 2x MLP.
// Halves combined with shfl_xor(...,32); lanes 0-31 store float4.
// ---------------------------------------------------------------------------
__global__ __launch_bounds__(256, 8) void gather_kernel(
    const unsigned short* __restrict__ Mk, const float* __restrict__ H,
    const float* __restrict__ sv, const float* __restrict__ rv,
    float* __restrict__ out)
{
    __shared__ float2 s_l[4][RCAP];   // .x = weight, .y = column index (bits)

    const int wave = threadIdx.x >> 6;
    const int lane = threadIdx.x & 63;
    const int i    = blockIdx.x * 4 + wave;

    // lane holds mask words k = lane*8 .. lane*8+7 (one 16B load)
    const uint4 mw = ((const uint4*)(Mk + (size_t)i * 512))[lane];
    unsigned wv[4] = {mw.x, mw.y, mw.z, mw.w};

    const int c = __popc(wv[0]) + __popc(wv[1]) + __popc(wv[2]) + __popc(wv[3]);

    // single wave inclusive scan
    int scan = c;
    #pragma unroll
    for (int off = 1; off < 64; off <<= 1) {
        const int t = __shfl_up(scan, off);
        if (lane >= off) scan += t;
    }
    int base = scan - c;                 // exclusive offset
    int cnt  = __shfl(scan, 63);         // wave-uniform total
    cnt = (cnt < RCAP) ? cnt : RCAP;

    // scatter: decode set bits -> columns
    #pragma unroll
    for (int widx = 0; widx < 4; ++widx) {
        unsigned mm = wv[widx];
        while (mm) {
            const int p = __ffs(mm) - 1;
            mm &= mm - 1;
            const int k = lane * 8 + widx * 2 + (p >> 4);  // mask word index
            const int b = p & 15;
            const int col = ((k >> 6) << 10) + ((b >> 2) << 8) + ((k & 63) << 2) + (b & 3);
            if (base < RCAP) s_l[wave][base].y = __int_as_float(col);
            ++base;
        }
    }

    // ---- softmax (<=4 entries per lane) ----
    const float si = sv[i];
    float zv[4];
    #pragma unroll
    for (int k = 0; k < 4; ++k) {
        const int p = lane + 64 * k;
        const bool act = (p < cnt);
        const int j = act ? __float_as_int(s_l[wave][p].y) : 0;
        float z = si + rv[j];
        z = (z > 0.0f) ? z : ALPHA * z;
        zv[k] = act ? z : -3.0e38f;
    }
    float lm = fmaxf(fmaxf(zv[0], zv[1]), fmaxf(zv[2], zv[3]));
    #pragma unroll
    for (int off = 32; off > 0; off >>= 1) lm = fmaxf(lm, __shfl_xor(lm, off));

    float sl = 0.0f;
    float wv4[4];
    #pragma unroll
    for (int k = 0; k < 4; ++k) {
        const int p = lane + 64 * k;
        const float w = (p < cnt) ? __expf(zv[k] - lm) : 0.0f;
        wv4[k] = w;
        sl += w;
    }
    #pragma unroll
    for (int off = 32; off > 0; off >>= 1) sl += __shfl_xor(sl, off);
    const float inv = 1.0f / sl;

    #pragma unroll
    for (int k = 0; k < 4; ++k) {
        const int p = lane + 64 * k;
        if (p < cnt) s_l[wave][p].x = wv4[k] * inv;
    }

    // ---- weighted gather: 2 entries/trip, lane owns float4 of features ----
    const int sub = lane >> 5;          // which entry of the pair
    const int fb  = (lane & 31) * 4;    // feature base (0..124)
    float4 acc = make_float4(0.0f, 0.0f, 0.0f, 0.0f);
    #pragma unroll 8
    for (int p = sub; p < cnt; p += 2) {
        const float2 wj = s_l[wave][p];             // 2-addr LDS read (free)
        const int   j  = __float_as_int(wj.y);
        const float4 h = *(const float4*)&H[(size_t)j * D + fb];
        acc.x += wj.x * h.x;
        acc.y += wj.x * h.y;
        acc.z += wj.x * h.z;
        acc.w += wj.x * h.w;
    }
    // combine the two halves (lane ^ 32 holds the other parity, same feats)
    acc.x += __shfl_xor(acc.x, 32);
    acc.y += __shfl_xor(acc.y, 32);
    acc.z += __shfl_xor(acc.z, 32);
    acc.w += __shfl_xor(acc.w, 32);
    if (sub == 0)
        *(float4*)&out[(size_t)i * D + fb] = acc;
}

extern "C" void kernel_launch(void* const* d_in, const int* in_sizes, int n_in,
                              void* d_out, int out_size, void* d_ws, size_t ws_size,
                              hipStream_t stream) {
    const float* X   = (const float*)d_in[0];
    const float* A   = (const float*)d_in[1];
    const float* W   = (const float*)d_in[2];
    const float* b   = (const float*)d_in[3];
    const float* a_s = (const float*)d_in[4];
    const float* a_r = (const float*)d_in[5];
    float* out = (float*)d_out;

    float* H  = (float*)d_ws;                         // N*D floats   (4 MB)
    float* sv = H + (size_t)N * D;                    // N floats
    float* rv = sv + N;                               // N floats
    unsigned short* Mk = (unsigned short*)(rv + N);   // N*512 u16    (8 MB)

    linear_kernel<<<256, 256, 0, stream>>>(X, W, b, a_s, a_r, H, sv, rv);
    mask_kernel<<<N / 4, 256, 0, stream>>>(A, Mk);
    gather_kernel<<<N / 4, 256, 0, stream>>>(Mk, H, sv, rv, out);
}

// Round 10
// 379.084 us; speedup vs baseline: 1.0930x; 1.0116x over previous
//
#include <hip/hip_runtime.h>

#define N 8192
#define D 128
#define ALPHA 0.2f
#define RCAP 256   // per-row nnz capacity; E[nnz]=83, sd=9

typedef float fx4 __attribute__((ext_vector_type(4)));   // native vec type for nontemporal builtins

// ---------------------------------------------------------------------------
// Kernel 1: H = X @ W^T + b ; s = H @ a_s ; r = H @ a_r   (unchanged)
// ---------------------------------------------------------------------------
__global__ __launch_bounds__(256) void linear_kernel(
    const float* __restrict__ X, const float* __restrict__ W,
    const float* __restrict__ b, const float* __restrict__ a_s,
    const float* __restrict__ a_r,
    float* __restrict__ H, float* __restrict__ sv, float* __restrict__ rv)
{
    __shared__ float Xs[128 * 36];
    __shared__ float Ws[64 * 132];

    const int tid = threadIdx.x;
    const int i0  = blockIdx.x * 32;

    for (int idx = tid; idx < 32 * 128; idx += 256) {
        const int row = idx >> 7, k = idx & 127;
        Xs[k * 36 + row] = X[(i0 + row) * D + k];
    }

    float acc[4][4] = {};
    const int ty = tid >> 5, tx = tid & 31;
    const int rbase = ty * 4, cbase = tx * 4;

    for (int kb = 0; kb < 2; ++kb) {
        __syncthreads();
        for (int idx = tid; idx < 64 * 128; idx += 256) {
            const int o = idx >> 6, kk = idx & 63;
            Ws[kk * 132 + o] = W[o * D + kb * 64 + kk];
        }
        __syncthreads();
        #pragma unroll
        for (int kk = 0; kk < 64; ++kk) {
            const float4 xv = *(const float4*)&Xs[(kb * 64 + kk) * 36 + rbase];
            const float4 wv = *(const float4*)&Ws[kk * 132 + cbase];
            const float xr[4] = {xv.x, xv.y, xv.z, xv.w};
            const float wc[4] = {wv.x, wv.y, wv.z, wv.w};
            #pragma unroll
            for (int r = 0; r < 4; ++r)
                #pragma unroll
                for (int c = 0; c < 4; ++c)
                    acc[r][c] += xr[r] * wc[c];
        }
    }

    const float4 bv  = *(const float4*)&b[cbase];
    const float4 asv = *(const float4*)&a_s[cbase];
    const float4 arv = *(const float4*)&a_r[cbase];
    #pragma unroll
    for (int r = 0; r < 4; ++r) {
        float4 h;
        h.x = acc[r][0] + bv.x;
        h.y = acc[r][1] + bv.y;
        h.z = acc[r][2] + bv.z;
        h.w = acc[r][3] + bv.w;
        *(float4*)&H[(size_t)(i0 + rbase + r) * D + cbase] = h;
        float ps = h.x * asv.x + h.y * asv.y + h.z * asv.z + h.w * asv.w;
        float pr = h.x * arv.x + h.y * arv.y + h.z * arv.z + h.w * arv.w;
        #pragma unroll
        for (int off = 16; off > 0; off >>= 1) {
            ps += __shfl_xor(ps, off);
            pr += __shfl_xor(pr, off);
        }
        if (tx == 0) {
            sv[i0 + rbase + r] = ps;
            rv[i0 + rbase + r] = pr;
        }
    }
}

// ---------------------------------------------------------------------------
// Kernel 2: FUSED stream+softmax+gather, ONE WAVE PER ROW, no Mk round-trip.
// Stream phase: 32 nt float4 loads/lane (fully unrolled -> compile-time
// register indices, no scratch), per-lane 128-bit mask accumulated in uint4.
// ZERO cross-lane ops in the stream (R5's per-4KB scan was the serializer).
// Tail: ONE prefix scan, bit-decode -> LDS list, shuffle softmax,
// 2-entry/trip float4 gather (R9).
// Lane mask bit layout: wv[it>>1], halfword (it&1), bit b covers
// col = it*1024 + (b>>2)*256 + lane*4 + (b&3).
// ---------------------------------------------------------------------------
__global__ __launch_bounds__(256, 6) void attn_fused(
    const float* __restrict__ A, const float* __restrict__ H,
    const float* __restrict__ sv, const float* __restrict__ rv,
    float* __restrict__ out)
{
    __shared__ float2 s_l[4][RCAP];   // .x = weight, .y = column index (bits)

    const int wave = threadIdx.x >> 6;
    const int lane = threadIdx.x & 63;
    const int i    = blockIdx.x * 4 + wave;

    const fx4* __restrict__ Arow = (const fx4*)(A + (size_t)i * N);

    // ---- stream phase: build per-lane 128-bit mask, no cross-lane ops ----
    unsigned wv[4] = {0u, 0u, 0u, 0u};
    #pragma unroll
    for (int it = 0; it < 8; ++it) {
        const fx4 a0 = __builtin_nontemporal_load(&Arow[it * 256 +   0 + lane]);
        const fx4 a1 = __builtin_nontemporal_load(&Arow[it * 256 +  64 + lane]);
        const fx4 a2 = __builtin_nontemporal_load(&Arow[it * 256 + 128 + lane]);
        const fx4 a3 = __builtin_nontemporal_load(&Arow[it * 256 + 192 + lane]);
        unsigned m = 0;
        m |= (a0.x != 0.0f ? 1u : 0u) << 0;
        m |= (a0.y != 0.0f ? 1u : 0u) << 1;
        m |= (a0.z != 0.0f ? 1u : 0u) << 2;
        m |= (a0.w != 0.0f ? 1u : 0u) << 3;
        m |= (a1.x != 0.0f ? 1u : 0u) << 4;
        m |= (a1.y != 0.0f ? 1u : 0u) << 5;
        m |= (a1.z != 0.0f ? 1u : 0u) << 6;
        m |= (a1.w != 0.0f ? 1u : 0u) << 7;
        m |= (a2.x != 0.0f ? 1u : 0u) << 8;
        m |= (a2.y != 0.0f ? 1u : 0u) << 9;
        m |= (a2.z != 0.0f ? 1u : 0u) << 10;
        m |= (a2.w != 0.0f ? 1u : 0u) << 11;
        m |= (a3.x != 0.0f ? 1u : 0u) << 12;
        m |= (a3.y != 0.0f ? 1u : 0u) << 13;
        m |= (a3.z != 0.0f ? 1u : 0u) << 14;
        m |= (a3.w != 0.0f ? 1u : 0u) << 15;
        wv[it >> 1] |= m << ((it & 1) * 16);   // it constant -> reg index
    }

    // ---- one wave prefix scan over per-lane counts ----
    const int c = __popc(wv[0]) + __popc(wv[1]) + __popc(wv[2]) + __popc(wv[3]);
    int scan = c;
    #pragma unroll
    for (int off = 1; off < 64; off <<= 1) {
        const int t = __shfl_up(scan, off);
        if (lane >= off) scan += t;
    }
    int base = scan - c;                 // exclusive offset
    int cnt  = __shfl(scan, 63);         // wave-uniform total
    cnt = (cnt < RCAP) ? cnt : RCAP;

    // ---- decode set bits -> columns in LDS list ----
    #pragma unroll
    for (int widx = 0; widx < 4; ++widx) {
        unsigned mm = wv[widx];
        while (mm) {
            const int p = __ffs(mm) - 1;
            mm &= mm - 1;
            const int it = widx * 2 + (p >> 4);
            const int b  = p & 15;
            const int col = it * 1024 + ((b >> 2) << 8) + (lane << 2) + (b & 3);
            if (base < RCAP) s_l[wave][base].y = __int_as_float(col);
            ++base;
        }
    }

    // ---- softmax (<=4 entries per lane) ----
    const float si = sv[i];
    float zv[4];
    #pragma unroll
    for (int k = 0; k < 4; ++k) {
        const int p = lane + 64 * k;
        const bool act = (p < cnt);
        const int j = act ? __float_as_int(s_l[wave][p].y) : 0;
        float z = si + rv[j];
        z = (z > 0.0f) ? z : ALPHA * z;
        zv[k] = act ? z : -3.0e38f;
    }
    float lm = fmaxf(fmaxf(zv[0], zv[1]), fmaxf(zv[2], zv[3]));
    #pragma unroll
    for (int off = 32; off > 0; off >>= 1) lm = fmaxf(lm, __shfl_xor(lm, off));

    float sl = 0.0f;
    float wv4[4];
    #pragma unroll
    for (int k = 0; k < 4; ++k) {
        const int p = lane + 64 * k;
        const float w = (p < cnt) ? __expf(zv[k] - lm) : 0.0f;
        wv4[k] = w;
        sl += w;
    }
    #pragma unroll
    for (int off = 32; off > 0; off >>= 1) sl += __shfl_xor(sl, off);
    const float inv = 1.0f / sl;

    #pragma unroll
    for (int k = 0; k < 4; ++k) {
        const int p = lane + 64 * k;
        if (p < cnt) s_l[wave][p].x = wv4[k] * inv;
    }

    // ---- weighted gather: 2 entries/trip, lane owns a float4 of features ----
    const int sub = lane >> 5;          // which entry of the pair
    const int fb  = (lane & 31) * 4;    // feature base (0..124)
    float4 acc = make_float4(0.0f, 0.0f, 0.0f, 0.0f);
    #pragma unroll 8
    for (int p = sub; p < cnt; p += 2) {
        const float2 wj = s_l[wave][p];             // 2-addr LDS read (free)
        const int   j  = __float_as_int(wj.y);
        const float4 h = *(const float4*)&H[(size_t)j * D + fb];
        acc.x += wj.x * h.x;
        acc.y += wj.x * h.y;
        acc.z += wj.x * h.z;
        acc.w += wj.x * h.w;
    }
    acc.x += __shfl_xor(acc.x, 32);
    acc.y += __shfl_xor(acc.y, 32);
    acc.z += __shfl_xor(acc.z, 32);
    acc.w += __shfl_xor(acc.w, 32);
    if (sub == 0)
        *(float4*)&out[(size_t)i * D + fb] = acc;
}

extern "C" void kernel_launch(void* const* d_in, const int* in_sizes, int n_in,
                              void* d_out, int out_size, void* d_ws, size_t ws_size,
                              hipStream_t stream) {
    const float* X   = (const float*)d_in[0];
    const float* A   = (const float*)d_in[1];
    const float* W   = (const float*)d_in[2];
    const float* b   = (const float*)d_in[3];
    const float* a_s = (const float*)d_in[4];
    const float* a_r = (const float*)d_in[5];
    float* out = (float*)d_out;

    float* H  = (float*)d_ws;               // N*D floats = 4 MB
    float* sv = H + (size_t)N * D;          // N floats
    float* rv = sv + N;                     // N floats

    linear_kernel<<<256, 256, 0, stream>>>(X, W, b, a_s, a_r, H, sv, rv);
    attn_fused<<<N / 4, 256, 0, stream>>>(A, H, sv, rv, out);
}

// Round 11
// 374.080 us; speedup vs baseline: 1.1077x; 1.0134x over previous
//
#include <hip/hip_runtime.h>

#define N 8192
#define D 128
#define ALPHA 0.2f
#define RCAP 256   // per-row nnz capacity; E[nnz]=83, sd=9 -> 19 sigma

typedef float fx4 __attribute__((ext_vector_type(4)));

// ---------------------------------------------------------------------------
// Kernel 1: H = X @ W^T + b ; s = H @ a_s ; r = H @ a_r   (unchanged)
// ---------------------------------------------------------------------------
__global__ __launch_bounds__(256) void linear_kernel(
    const float* __restrict__ X, const float* __restrict__ W,
    const float* __restrict__ b, const float* __restrict__ a_s,
    const float* __restrict__ a_r,
    float* __restrict__ H, float* __restrict__ sv, float* __restrict__ rv)
{
    __shared__ float Xs[128 * 36];
    __shared__ float Ws[64 * 132];

    const int tid = threadIdx.x;
    const int i0  = blockIdx.x * 32;

    for (int idx = tid; idx < 32 * 128; idx += 256) {
        const int row = idx >> 7, k = idx & 127;
        Xs[k * 36 + row] = X[(i0 + row) * D + k];
    }

    float acc[4][4] = {};
    const int ty = tid >> 5, tx = tid & 31;
    const int rbase = ty * 4, cbase = tx * 4;

    for (int kb = 0; kb < 2; ++kb) {
        __syncthreads();
        for (int idx = tid; idx < 64 * 128; idx += 256) {
            const int o = idx >> 6, kk = idx & 63;
            Ws[kk * 132 + o] = W[o * D + kb * 64 + kk];
        }
        __syncthreads();
        #pragma unroll
        for (int kk = 0; kk < 64; ++kk) {
            const float4 xv = *(const float4*)&Xs[(kb * 64 + kk) * 36 + rbase];
            const float4 wv = *(const float4*)&Ws[kk * 132 + cbase];
            const float xr[4] = {xv.x, xv.y, xv.z, xv.w};
            const float wc[4] = {wv.x, wv.y, wv.z, wv.w};
            #pragma unroll
            for (int r = 0; r < 4; ++r)
                #pragma unroll
                for (int c = 0; c < 4; ++c)
                    acc[r][c] += xr[r] * wc[c];
        }
    }

    const float4 bv  = *(const float4*)&b[cbase];
    const float4 asv = *(const float4*)&a_s[cbase];
    const float4 arv = *(const float4*)&a_r[cbase];
    #pragma unroll
    for (int r = 0; r < 4; ++r) {
        float4 h;
        h.x = acc[r][0] + bv.x;
        h.y = acc[r][1] + bv.y;
        h.z = acc[r][2] + bv.z;
        h.w = acc[r][3] + bv.w;
        *(float4*)&H[(size_t)(i0 + rbase + r) * D + cbase] = h;
        float ps = h.x * asv.x + h.y * asv.y + h.z * asv.z + h.w * asv.w;
        float pr = h.x * arv.x + h.y * arv.y + h.z * arv.z + h.w * arv.w;
        #pragma unroll
        for (int off = 16; off > 0; off >>= 1) {
            ps += __shfl_xor(ps, off);
            pr += __shfl_xor(pr, off);
        }
        if (tx == 0) {
            sv[i0 + rbase + r] = ps;
            rv[i0 + rbase + r] = pr;
        }
    }
}

// ---------------------------------------------------------------------------
// Kernel 2: fused attention, ONE BLOCK (4 waves) PER ROW.
// Each wave streams only 8 KB = 8 independent nt loads — all issuable before
// the first waitcnt (tests the per-wave stream-serialization theory).
// Wave w covers float4 idx [w*512,(w+1)*512); lane loads q*64+lane, q=0..7;
// mask bit q*4+e covers col = w*2048 + q*256 + lane*4 + e.
// Tail: per-wave prefix scan + cross-wave offsets (LDS), block softmax,
// gather over 8 half-waves + LDS combine.
// ---------------------------------------------------------------------------
__global__ __launch_bounds__(256) void attn_fused(
    const float* __restrict__ A, const float* __restrict__ H,
    const float* __restrict__ sv, const float* __restrict__ rv,
    float* __restrict__ out)
{
    __shared__ float2 s_l[RCAP];        // .x weight, .y col bits (2 KB)
    __shared__ int    s_wcnt[4];
    __shared__ float  s_red[8];
    __shared__ float4 s_part[4][32];    // per-wave gather partials (2 KB)

    const int tid  = threadIdx.x;
    const int wave = tid >> 6;
    const int lane = tid & 63;
    const int i    = blockIdx.x;

    const fx4* __restrict__ Arow = (const fx4*)(A + (size_t)i * N);

    // ---- stream: 8 fully-unrolled nt loads, per-lane 32-bit mask ----
    unsigned m = 0;
    #pragma unroll
    for (int q = 0; q < 8; ++q) {
        const fx4 a = __builtin_nontemporal_load(&Arow[wave * 512 + q * 64 + lane]);
        m |= (a.x != 0.0f ? 1u : 0u) << (q * 4 + 0);
        m |= (a.y != 0.0f ? 1u : 0u) << (q * 4 + 1);
        m |= (a.z != 0.0f ? 1u : 0u) << (q * 4 + 2);
        m |= (a.w != 0.0f ? 1u : 0u) << (q * 4 + 3);
    }

    // ---- per-wave inclusive scan; cross-wave totals via LDS ----
    const int c = __popc(m);
    int scan = c;
    #pragma unroll
    for (int off = 1; off < 64; off <<= 1) {
        const int t = __shfl_up(scan, off);
        if (lane >= off) scan += t;
    }
    if (lane == 63) s_wcnt[wave] = scan;      // wave total
    __syncthreads();
    int base = scan - c;
    #pragma unroll
    for (int w2 = 0; w2 < 4; ++w2)
        if (w2 < wave) base += s_wcnt[w2];
    int cnt = s_wcnt[0] + s_wcnt[1] + s_wcnt[2] + s_wcnt[3];
    cnt = (cnt < RCAP) ? cnt : RCAP;

    // ---- decode set bits -> column list ----
    {
        unsigned mm = m;
        while (mm) {
            const int p = __ffs(mm) - 1;
            mm &= mm - 1;
            const int col = wave * 2048 + ((p >> 2) << 8) + (lane << 2) + (p & 3);
            if (base < RCAP) s_l[base].y = __int_as_float(col);
            ++base;
        }
    }
    __syncthreads();

    // ---- softmax: thread t owns entry t (cnt <= 256) ----
    const float si = sv[i];
    float z = -3.0e38f;
    if (tid < cnt) {
        const int j = __float_as_int(s_l[tid].y);
        z = si + rv[j];
        z = (z > 0.0f) ? z : ALPHA * z;
    }
    float lm = z;
    #pragma unroll
    for (int off = 32; off > 0; off >>= 1) lm = fmaxf(lm, __shfl_xor(lm, off));
    if (lane == 0) s_red[wave] = lm;
    __syncthreads();
    const float M = fmaxf(fmaxf(s_red[0], s_red[1]), fmaxf(s_red[2], s_red[3]));

    const float w = (tid < cnt) ? __expf(z - M) : 0.0f;
    float sl = w;
    #pragma unroll
    for (int off = 32; off > 0; off >>= 1) sl += __shfl_xor(sl, off);
    if (lane == 0) s_red[4 + wave] = sl;
    __syncthreads();
    const float inv = 1.0f / (s_red[4] + s_red[5] + s_red[6] + s_red[7]);
    if (tid < cnt) s_l[tid].x = w * inv;
    __syncthreads();

    // ---- gather: 8 half-waves, entry stride 8; lane&31 owns a float4 ----
    const int hw = tid >> 5;            // 0..7
    const int fs = tid & 31;            // float4 feature slot
    float4 acc = make_float4(0.0f, 0.0f, 0.0f, 0.0f);
    #pragma unroll 4
    for (int p = hw; p < cnt; p += 8) {
        const float2 wj = s_l[p];
        const int   j  = __float_as_int(wj.y);
        const float4 h = *(const float4*)&H[(size_t)j * D + fs * 4];
        acc.x += wj.x * h.x;
        acc.y += wj.x * h.y;
        acc.z += wj.x * h.z;
        acc.w += wj.x * h.w;
    }
    // combine half-wave pairs within each wave
    acc.x += __shfl_xor(acc.x, 32);
    acc.y += __shfl_xor(acc.y, 32);
    acc.z += __shfl_xor(acc.z, 32);
    acc.w += __shfl_xor(acc.w, 32);
    if ((lane >> 5) == 0) s_part[wave][fs] = acc;
    __syncthreads();
    // final 4-way combine + store by first 32 threads
    if (tid < 32) {
        float4 v = s_part[0][tid];
        const float4 v1 = s_part[1][tid];
        const float4 v2 = s_part[2][tid];
        const float4 v3 = s_part[3][tid];
        v.x += v1.x + v2.x + v3.x;
        v.y += v1.y + v2.y + v3.y;
        v.z += v1.z + v2.z + v3.z;
        v.w += v1.w + v2.w + v3.w;
        *(float4*)&out[(size_t)i * D + tid * 4] = v;
    }
}

extern "C" void kernel_launch(void* const* d_in, const int* in_sizes, int n_in,
                              void* d_out, int out_size, void* d_ws, size_t ws_size,
                              hipStream_t stream) {
    const float* X   = (const float*)d_in[0];
    const float* A   = (const float*)d_in[1];
    const float* W   = (const float*)d_in[2];
    const float* b   = (const float*)d_in[3];
    const float* a_s = (const float*)d_in[4];
    const float* a_r = (const float*)d_in[5];
    float* out = (float*)d_out;

    float* H  = (float*)d_ws;               // N*D floats = 4 MB
    float* sv = H + (size_t)N * D;          // N floats
    float* rv = sv + N;                     // N floats

    linear_kernel<<<256, 256, 0, stream>>>(X, W, b, a_s, a_r, H, sv, rv);
    attn_fused<<<N, 256, 0, stream>>>(A, H, sv, rv, out);
}